// Round 8
// baseline (273.303 us; speedup 1.0000x reference)
//
#include <hip/hip_runtime.h>
#include <hip/hip_bf16.h>

// Conv1d as implicit GEMM on MFMA bf16 — R8.
// out[n,f,t] = sum_{c,k} x[n,c,t+k] * w[f,c,k] + b[f]
// N=32, C=64, W=4096, F=128, WW=64, out_W=4033. Output fp32.
//
// R8 vs R6/R7: occupancy attack. Wave tile 128t x 32f (acc=64 regs), block
// 256t x 64f, grid 1024 (z = f-half), __launch_bounds__(256,3) -> 3 blocks/CU
// = 12 waves/CU (R6 was 8 with acc=128). B back on the DMA->LDS path (R7's
// global-B regressed: L1 can't feed 8KB/wave/ch). x-prep dropped: A-windows
// load fp32 directly + v_cvt_pk_bf16_f32 pack; prep converts only w (1MB ws).

#define C_TOT   64
#define F_TOT   128
#define KW      64
#define OUT_W   4033
#define W_IN    4096
#define N_BATCH 32
#define T_BLK   256
#define CH      2             // channels per pipeline stage

typedef __attribute__((ext_vector_type(8))) short  short8;
typedef __attribute__((ext_vector_type(4))) float  floatx4;

union Frag { unsigned int u[4]; short8 v; };

__device__ inline unsigned short f32_to_bf16(float f) {
  unsigned int u = __float_as_uint(f);
  u += 0x7FFF + ((u >> 16) & 1);
  return (unsigned short)(u >> 16);
}

__device__ inline unsigned int pack2(float a, float bb) {
  __hip_bfloat162 h = __float22bfloat162_rn(make_float2(a, bb));  // v_cvt_pk_bf16_f32
  return *(unsigned int*)&h;   // low 16 = a, high 16 = bb
}

__device__ inline void async16(const unsigned short* g, unsigned short* l) {
  __builtin_amdgcn_global_load_lds(
      (const __attribute__((address_space(1))) unsigned int*)g,
      (__attribute__((address_space(3))) unsigned int*)l, 16, 0, 0);
}

// ---- prep: w fp32 [f][c][k] -> bf16 [c][fh][f&63][(k>>3)^(f&7)][k&7] ----
__global__ __launch_bounds__(256) void conv1d_prep(
    const float* __restrict__ w, unsigned short* __restrict__ wsw) {
  int i4 = blockIdx.x * 256 + threadIdx.x;   // float4 index into w
  if (i4 < F_TOT * C_TOT * KW / 4) {
    int k4 = (i4 & 15) * 4;
    int c  = (i4 >> 4) & 63;
    int f  = i4 >> 10;
    float4 v = *(const float4*)&w[(size_t)i4 * 4];
    ushort4 o;
    o.x = f32_to_bf16(v.x); o.y = f32_to_bf16(v.y);
    o.z = f32_to_bf16(v.z); o.w = f32_to_bf16(v.w);
    int fh = f >> 6, fl = f & 63;
    int chunk = (k4 >> 3) ^ (f & 7);
    *(ushort4*)&wsw[((size_t)((c * 2 + fh) * 64 + fl)) * 64 + chunk * 8 + (k4 & 7)] = o;
  }
}

// ---------------- main GEMM ----------------
__global__ __launch_bounds__(256, 3) void conv1d_mfma(
    const float* __restrict__ x, const unsigned short* __restrict__ wsw,
    const float* __restrict__ b, float* __restrict__ out) {
  __shared__ union SM {
    unsigned short wls[2][CH * 64 * KW];   // 2 x 8192 shorts = 32 KB (w dbuf)
    float tr[32 * 256];                    // 32 KB transpose buffer (epilogue)
  } sm;

  const int tid  = threadIdx.x;
  const int lane = tid & 63;
  const int wv   = tid >> 6;     // 0..3
  const int q    = lane >> 4;    // 0..3
  const int col  = lane & 15;
  const int n    = blockIdx.y;
  const int t0   = blockIdx.x * T_BLK;
  const int fh   = blockIdx.z;   // f half (64 f)
  const int th   = wv >> 1;      // t half (128 t)
  const int fq   = wv & 1;       // f quarter (32 f)

  floatx4 acc[8][2];             // [ms][ft]
#pragma unroll
  for (int ms = 0; ms < 8; ++ms)
#pragma unroll
    for (int ft = 0; ft < 2; ++ft) acc[ms][ft] = (floatx4)0.0f;

  // A base t (elements): lane's window start for h=0
  const int tb = t0 + 8 * col + 128 * th + 8 * q;
  const float* xnb = x + (size_t)n * C_TOT * W_IN;

  // w DMA: 4 asyncs/thread per stage; g = s*256+tid; chl = g>>9 (wave-uniform)
#define STAGE_W(cg, p)                                                          \
  {                                                                             \
    _Pragma("unroll")                                                           \
    for (int s = 0; s < 4; ++s) {                                               \
      int g   = s * 256 + tid;                                                  \
      int chl = g >> 9;                                                         \
      int wo  = (g & 511) * 8;                                                  \
      async16(wsw + ((size_t)(((cg) * CH + chl) * 2 + fh)) * 4096 + wo,         \
              &sm.wls[p][g * 8]);                                               \
    }                                                                           \
  }

#define COMPUTE(p)                                                              \
  {                                                                             \
    _Pragma("unroll")                                                           \
    for (int chl = 0; chl < CH; ++chl) {                                        \
      const float* xr = xnb + (size_t)(cg * CH + chl) * W_IN;                   \
      const unsigned short* wpb = &sm.wls[p][chl * 4096];                       \
      _Pragma("unroll")                                                         \
      for (int h = 0; h < 2; ++h) {                                             \
        const int gt = tb + 32 * h;                                             \
        float4 v0 = *(const float4*)(xr + min(gt,      W_IN - 4));              \
        float4 v1 = *(const float4*)(xr + min(gt + 4,  W_IN - 4));              \
        float4 v2 = *(const float4*)(xr + min(gt + 8,  W_IN - 4));              \
        float4 v3 = *(const float4*)(xr + min(gt + 12, W_IN - 4));              \
        const unsigned int D[8] = {                                             \
            pack2(v0.x, v0.y), pack2(v0.z, v0.w),                               \
            pack2(v1.x, v1.y), pack2(v1.z, v1.w),                               \
            pack2(v2.x, v2.y), pack2(v2.z, v2.w),                               \
            pack2(v3.x, v3.y), pack2(v3.z, v3.w)};                              \
        Frag A[8];                                                              \
        _Pragma("unroll")                                                       \
        for (int s = 0; s < 4; ++s)                                             \
          _Pragma("unroll")                                                     \
          for (int i = 0; i < 4; ++i) {                                         \
            A[2 * s].u[i]     = D[s + i];                                       \
            A[2 * s + 1].u[i] = (D[s + i] >> 16) | (D[s + i + 1] << 16);        \
          }                                                                     \
        const int bs = ((h * 4 + q) ^ (col & 7)) * 8;                           \
        _Pragma("unroll")                                                       \
        for (int ft = 0; ft < 2; ++ft) {                                        \
          const short8 bf =                                                     \
              *(const short8*)&wpb[(fq * 32 + ft * 16 + col) * KW + bs];        \
          _Pragma("unroll")                                                     \
          for (int ms = 0; ms < 8; ++ms)                                        \
            acc[ms][ft] = __builtin_amdgcn_mfma_f32_16x16x32_bf16(              \
                A[ms].v, bf, acc[ms][ft], 0, 0, 0);                             \
        }                                                                       \
      }                                                                         \
    }                                                                           \
  }

  STAGE_W(0, 0)
  __syncthreads();

#pragma unroll 1
  for (int cg = 0; cg < C_TOT / CH; ++cg) {
    const int p = cg & 1;
    if (cg < C_TOT / CH - 1) STAGE_W(cg + 1, p ^ 1)
    COMPUTE(p)
    __syncthreads();
  }

  // ---- epilogue: XOR-swizzled LDS transpose to [f][t], coalesced stores ----
  // acc[ms][ft][r]: t_loc = 32q + 8r + ms + 128*th, f_loc = fq*32 + ft*16 + col
  const int fs_w  = fq * 16 + col;      // f-slot for writes (0..31)
  const int fs_r  = tid >> 3;           // f-slot for reads (0..31)
  const int seg   = tid & 7;
  const size_t ob = ((size_t)n * F_TOT) * OUT_W;

#pragma unroll
  for (int j = 0; j < 2; ++j) {         // round j handles ft == j (compile-time)
#pragma unroll
    for (int r = 0; r < 4; ++r)
#pragma unroll
      for (int g2 = 0; g2 < 2; ++g2) {
        float4 vv;
        vv.x = acc[g2 * 4 + 0][j][r];
        vv.y = acc[g2 * 4 + 1][j][r];
        vv.z = acc[g2 * 4 + 2][j][r];
        vv.w = acc[g2 * 4 + 3][j][r];
        int chunk = 8 * q + 2 * r + g2 + 32 * th;      // t granule (0..63)
        *(float4*)&sm.tr[fs_w * 256 + ((chunk ^ (fs_w & 7)) << 2)] = vv;
      }
    __syncthreads();
    const int f = fh * 64 + (fs_r >> 4) * 32 + j * 16 + (fs_r & 15);
    const float bias = b[f];
    const size_t obf = ob + (size_t)f * OUT_W;
#pragma unroll
    for (int j2 = 0; j2 < 8; ++j2) {
      int chunk = seg + 8 * j2;
      float4 vv = *(const float4*)&sm.tr[fs_r * 256 + ((chunk ^ (fs_r & 7)) << 2)];
      vv.x += bias; vv.y += bias; vv.z += bias; vv.w += bias;
      int t = t0 + chunk * 4;
      if (t + 3 < OUT_W) {
        *(float4*)&out[obf + t] = vv;
      } else {
        float e[4] = {vv.x, vv.y, vv.z, vv.w};
#pragma unroll
        for (int u = 0; u < 4; ++u)
          if (t + u < OUT_W) out[obf + t + u] = e[u];
      }
    }
    __syncthreads();
  }
}

extern "C" void kernel_launch(void* const* d_in, const int* in_sizes, int n_in,
                              void* d_out, int out_size, void* d_ws, size_t ws_size,
                              hipStream_t stream) {
  const float* x = (const float*)d_in[0];
  const float* w = (const float*)d_in[1];
  const float* b = (const float*)d_in[2];
  float* out = (float*)d_out;

  unsigned short* wsw = (unsigned short*)d_ws;   // 1 MB bf16 swizzled w

  conv1d_prep<<<(F_TOT * C_TOT * KW / 4 + 255) / 256, 256, 0, stream>>>(w, wsw);

  dim3 grid((OUT_W + T_BLK - 1) / T_BLK, N_BATCH, 2);  // 16 x 32 x 2 = 1024 blocks
  conv1d_mfma<<<grid, 256, 0, stream>>>(x, wsw, b, out);
}